// Round 1
// baseline (142.302 us; speedup 1.0000x reference)
//
#include <hip/hip_runtime.h>
#include <stdint.h>

typedef __attribute__((ext_vector_type(8))) short bf16x8;
typedef __attribute__((ext_vector_type(4))) float f32x4;

#define B_ 8
#define S_ 2048
#define D_ 2048
#define E_ 8
#define R_ 16
#define J_ 128
#define SCALING 1.0f

static __device__ __forceinline__ unsigned short f2bf(float f) {
  union { float f; uint32_t u; } v; v.f = f;
  uint32_t u = v.u;
  return (unsigned short)((u + 0x7FFFu + ((u >> 16) & 1u)) >> 16);
}
static __device__ __forceinline__ float bf2f(unsigned short h) {
  union { uint32_t u; float f; } v; v.u = ((uint32_t)h) << 16;
  return v.f;
}

// K0: convert lora_A -> Albf[j][d] bf16 (j = e*16+r, direct row-major reinterpret),
//     lora_B[e][d][r] -> BcT[d][j] bf16, zero pool accumulator.
__global__ void k_prep(const float* __restrict__ lA, const float* __restrict__ lB,
                       unsigned short* __restrict__ Albf, unsigned short* __restrict__ BcT,
                       float* __restrict__ pool) {
  int gid = blockIdx.x * blockDim.x + threadIdx.x;
  int stride = gridDim.x * blockDim.x;
  for (int i = gid; i < J_ * D_; i += stride) Albf[i] = f2bf(lA[i]);
  for (int o = gid; o < D_ * J_; o += stride) {
    int d = o >> 7; int rem = o & 127; int e = rem >> 4; int r = rem & 15;
    BcT[o] = f2bf(lB[(size_t)e * (D_ * R_) + d * R_ + r]);
  }
  for (int i = gid; i < B_ * D_; i += stride) pool[i] = 0.f;
}

// K1: mid[b][s][j] = sum_d x[b][s][d] * Albf[j][d]  (all 128 j), fused mean-pool partials.
__global__ __launch_bounds__(256) void k_mid(const float* __restrict__ x,
    const unsigned short* __restrict__ Albf, float* __restrict__ mid,
    float* __restrict__ pool) {
  __shared__ unsigned short As[32][72];   // x tile bf16, +8 pad
  __shared__ unsigned short Bs[128][72];  // Albf tile bf16, +8 pad
  __shared__ float tmpPool[4][64];
  __shared__ float poolL[2048];
  const int tid = threadIdx.x;
  const int b = blockIdx.y;
  const int s0 = blockIdx.x * 32;
  const int w = tid >> 6, lane = tid & 63;
  const int row16 = (w & 1) * 16, jbase = (w >> 1) * 64;
  const int lm = lane & 15, lk = (lane >> 4) * 8;
  for (int d = tid; d < 2048; d += 256) poolL[d] = 0.f;
  f32x4 acc[4] = {};
  const float* xb = x + ((size_t)b * S_ + s0) * D_;
  const int xr = tid >> 3, xc = (tid & 7) * 8;
  const int ajr = tid >> 1, ahb = (tid & 1) * 32;

  for (int kt = 0; kt < 32; ++kt) {
    const int d0 = kt * 64;
    // stage x tile (fp32 -> bf16)
    const float* xs = xb + (size_t)xr * D_ + d0 + xc;
    float4 v0 = *(const float4*)xs;
    float4 v1 = *(const float4*)(xs + 4);
    bf16x8 xw;
    xw[0] = f2bf(v0.x); xw[1] = f2bf(v0.y); xw[2] = f2bf(v0.z); xw[3] = f2bf(v0.w);
    xw[4] = f2bf(v1.x); xw[5] = f2bf(v1.y); xw[6] = f2bf(v1.z); xw[7] = f2bf(v1.w);
    *(bf16x8*)&As[xr][xc] = xw;
    // stage Albf tile
    const unsigned short* asrc = Albf + (size_t)ajr * D_ + d0 + ahb;
#pragma unroll
    for (int i = 0; i < 4; ++i)
      *(bf16x8*)&Bs[ajr][ahb + i * 8] = *(const bf16x8*)(asrc + i * 8);
    __syncthreads();
    // MFMA: m=s (16 rows), n=j (4 tiles of 16), k=d (2 sub-k of 32)
    bf16x8 a0 = *(const bf16x8*)&As[row16 + lm][lk];
    bf16x8 a1 = *(const bf16x8*)&As[row16 + lm][32 + lk];
#pragma unroll
    for (int nn = 0; nn < 4; ++nn) {
      bf16x8 b0 = *(const bf16x8*)&Bs[jbase + nn * 16 + lm][lk];
      bf16x8 b1 = *(const bf16x8*)&Bs[jbase + nn * 16 + lm][32 + lk];
      acc[nn] = __builtin_amdgcn_mfma_f32_16x16x32_bf16(a0, b0, acc[nn], 0, 0, 0);
      acc[nn] = __builtin_amdgcn_mfma_f32_16x16x32_bf16(a1, b1, acc[nn], 0, 0, 0);
    }
    // pooling partial: column sums over this tile's 32 rows
    {
      int c = tid & 63, g = tid >> 6;
      float s = 0.f;
#pragma unroll
      for (int i = 0; i < 8; ++i) s += bf2f(As[g * 8 + i][c]);
      tmpPool[g][c] = s;
    }
    __syncthreads();
    if (tid < 64)
      poolL[d0 + tid] += tmpPool[0][tid] + tmpPool[1][tid] + tmpPool[2][tid] + tmpPool[3][tid];
  }
  // store mid (C layout: col = lane&15, row = (lane>>4)*4 + q)
  float* mrow = mid + ((size_t)b * S_ + s0) * J_;
#pragma unroll
  for (int nn = 0; nn < 4; ++nn)
#pragma unroll
    for (int q = 0; q < 4; ++q)
      mrow[(size_t)(row16 + (lane >> 4) * 4 + q) * J_ + jbase + nn * 16 + lm] = acc[nn][q];
  __syncthreads();
  for (int d = tid; d < 2048; d += 256) atomicAdd(&pool[b * D_ + d], poolL[d]);
}

// K2: router -> coeff[b][j]
__global__ void k_router(const float* __restrict__ pool, const float* __restrict__ gw,
    const float* __restrict__ tb, const float* __restrict__ mb,
    const int* __restrict__ tid_p, const int* __restrict__ mid_p,
    float* __restrict__ coeff) {
  __shared__ float logitsL[64];
  const int t = threadIdx.x;
  const int be = t >> 2, q = t & 3;
  const int b = be >> 3, e = be & 7;
  const float* pp = pool + b * D_ + q * 512;
  const float* gp = gw + e * D_ + q * 512;
  float s = 0.f;
  for (int i = 0; i < 512; i += 4) {
    float4 pv = *(const float4*)(pp + i);
    float4 gv = *(const float4*)(gp + i);
    s += pv.x * gv.x + pv.y * gv.y + pv.z * gv.z + pv.w * gv.w;
  }
  s += __shfl_xor(s, 1);
  s += __shfl_xor(s, 2);
  if (q == 0)
    logitsL[be] = s * (1.f / (float)S_) + tb[(*tid_p) * E_ + e] + mb[(*mid_p) * E_ + e];
  __syncthreads();
  if (t < B_) {
    int b2 = t;
    float v[8];
#pragma unroll
    for (int e2 = 0; e2 < 8; ++e2) v[e2] = logitsL[b2 * 8 + e2];
    int i1 = 0;
#pragma unroll
    for (int e2 = 1; e2 < 8; ++e2) if (v[e2] > v[i1]) i1 = e2;
    int i2 = (i1 == 0) ? 1 : 0;
#pragma unroll
    for (int e2 = 0; e2 < 8; ++e2) if (e2 != i1 && v[e2] > v[i2]) i2 = e2;
    float dlt = v[i2] - v[i1];
    float ex = expf(dlt);
    float w1 = 1.f / (1.f + ex);
    float w2 = ex * w1;
    for (int j = 0; j < J_; ++j) {
      int e2 = j >> 4;
      float c = (e2 == i1) ? w1 : ((e2 == i2) ? w2 : 0.f);
      coeff[b2 * J_ + j] = c * SCALING;
    }
  }
}

// K3: out[b][s][d] = sum_j (coeff[b][j]*mid[b][s][j]) * BcT[d][j]
__global__ __launch_bounds__(256) void k_comb(const float* __restrict__ mid,
    const float* __restrict__ coeff, const unsigned short* __restrict__ BcT,
    float* __restrict__ out) {
  __shared__ unsigned short Pl[64][136];   // P tile bf16, +8 pad
  __shared__ unsigned short Bt[128][136];  // BcT tile bf16, +8 pad
  const int tid = threadIdx.x;
  const int n = blockIdx.x, m = blockIdx.y, b = blockIdx.z;
  // stage P = coeff * mid (fp32 -> bf16)
  {
    int r = tid & 63, jc = tid >> 6;
    int j0 = jc * 32;
    const float* mp = mid + ((size_t)b * S_ + m * 64 + r) * J_ + j0;
    const float* cp = coeff + b * J_ + j0;
#pragma unroll
    for (int h = 0; h < 4; ++h) {
      float4 m0 = *(const float4*)(mp + h * 8);
      float4 m1 = *(const float4*)(mp + h * 8 + 4);
      float4 c0 = *(const float4*)(cp + h * 8);
      float4 c1 = *(const float4*)(cp + h * 8 + 4);
      bf16x8 pw;
      pw[0] = f2bf(m0.x * c0.x); pw[1] = f2bf(m0.y * c0.y);
      pw[2] = f2bf(m0.z * c0.z); pw[3] = f2bf(m0.w * c0.w);
      pw[4] = f2bf(m1.x * c1.x); pw[5] = f2bf(m1.y * c1.y);
      pw[6] = f2bf(m1.z * c1.z); pw[7] = f2bf(m1.w * c1.w);
      *(bf16x8*)&Pl[r][j0 + h * 8] = pw;
    }
  }
  // stage BcT tile
  {
    int d = tid >> 1, hb = (tid & 1) * 64;
    const unsigned short* src = BcT + ((size_t)(n * 128 + d)) * J_ + hb;
#pragma unroll
    for (int i = 0; i < 8; ++i)
      *(bf16x8*)&Bt[d][hb + i * 8] = *(const bf16x8*)(src + i * 8);
  }
  __syncthreads();
  const int w = tid >> 6, lane = tid & 63;
  const int lm = lane & 15, lk = (lane >> 4) * 8;
  f32x4 acc[8] = {};
  bf16x8 af[4];
#pragma unroll
  for (int ks = 0; ks < 4; ++ks)
    af[ks] = *(const bf16x8*)&Pl[w * 16 + lm][ks * 32 + lk];
#pragma unroll
  for (int nn = 0; nn < 8; ++nn) {
#pragma unroll
    for (int ks = 0; ks < 4; ++ks) {
      bf16x8 bfr = *(const bf16x8*)&Bt[nn * 16 + lm][ks * 32 + lk];
      acc[nn] = __builtin_amdgcn_mfma_f32_16x16x32_bf16(af[ks], bfr, acc[nn], 0, 0, 0);
    }
  }
  float* op = out + ((size_t)b * S_ + m * 64 + w * 16) * D_ + n * 128;
#pragma unroll
  for (int nn = 0; nn < 8; ++nn)
#pragma unroll
    for (int q = 0; q < 4; ++q)
      op[(size_t)((lane >> 4) * 4 + q) * D_ + nn * 16 + lm] = acc[nn][q];
}

extern "C" void kernel_launch(void* const* d_in, const int* in_sizes, int n_in,
                              void* d_out, int out_size, void* d_ws, size_t ws_size,
                              hipStream_t stream) {
  const float* x   = (const float*)d_in[0];
  const float* gw  = (const float*)d_in[1];
  const float* tb  = (const float*)d_in[2];
  const float* mb  = (const float*)d_in[3];
  const float* lA  = (const float*)d_in[4];
  const float* lB  = (const float*)d_in[5];
  const int* tid_p = (const int*)d_in[6];
  const int* mid_p = (const int*)d_in[7];
  float* out = (float*)d_out;
  char* ws = (char*)d_ws;
  float* mid           = (float*)ws;                       // 8,388,608 B
  unsigned short* Albf = (unsigned short*)(ws + 8388608);  //   524,288 B
  unsigned short* BcT  = (unsigned short*)(ws + 8912896);  //   524,288 B
  float* pool          = (float*)(ws + 9437184);           //    65,536 B
  float* coeff         = (float*)(ws + 9502720);           //     4,096 B

  hipLaunchKernelGGL(k_prep, dim3(128), dim3(256), 0, stream, lA, lB, Albf, BcT, pool);
  hipLaunchKernelGGL(k_mid, dim3(64, 8), dim3(256), 0, stream, x, Albf, mid, pool);
  hipLaunchKernelGGL(k_router, dim3(1), dim3(256), 0, stream, pool, gw, tb, mb,
                     tid_p, mid_p, coeff);
  hipLaunchKernelGGL(k_comb, dim3(16, 32, 8), dim3(256), 0, stream, mid, coeff, BcT, out);
}